// Round 5
// baseline (138.267 us; speedup 1.0000x reference)
//
#include <hip/hip_runtime.h>
#include <math.h>

// SSAaligner: s[i,j] = -sum_d |x[i,d]-y[j,d]|, x from z_x(D,N), y from z_y(D,M)
// a = softmax_rows(s), b = softmax_cols(s), u = a+b-a*b, out = sum(u*s)/sum(u)
// D=256, N=M=1024. fp32 in, fp32 scalar out.
//
// R5: scompute reads y via LDS double-buffer (wave-coalesced staging, issued a
// full 8-d chunk ahead) instead of per-thread streamed global loads -- R3/R4's
// 30% VALUBusy was unhidden L2/L3 latency on those loads. Inner loop is pure
// LDS + VALU (36 cyc LDS vs 128 cyc VALU per d). Downstream passes at 512
// blocks for 2 blocks/CU.

#define DD 256
#define NN 1024
#define DS 4
#define CH 64          // d's per slab
#define NQ 256         // float4 per row
#define NSTRIPE 512    // column-partial stripes (2 rows each)

// ---------------- reductions ----------------
__device__ __forceinline__ float waveMax(float v) {
  #pragma unroll
  for (int off = 32; off; off >>= 1) v = fmaxf(v, __shfl_xor(v, off, 64));
  return v;
}
__device__ __forceinline__ float waveSum(float v) {
  #pragma unroll
  for (int off = 32; off; off >>= 1) v += __shfl_xor(v, off, 64);
  return v;
}
__device__ __forceinline__ float blockMax(float v, float* red) {
  v = waveMax(v);
  __syncthreads();
  if ((threadIdx.x & 63) == 0) red[threadIdx.x >> 6] = v;
  __syncthreads();
  return fmaxf(fmaxf(red[0], red[1]), fmaxf(red[2], red[3]));
}
__device__ __forceinline__ float blockSum(float v, float* red) {
  v = waveSum(v);
  __syncthreads();
  if ((threadIdx.x & 63) == 0) red[threadIdx.x >> 6] = v;
  __syncthreads();
  return red[0] + red[1] + red[2] + red[3];
}

// ---------------- fast path ----------------

// Tile 32 rows x 256 cols x 64 d. Thread: 8 rows x 4 cols. Grid (4,32,4)=512
// blocks -> 2 blocks/CU, 8 waves/CU. y staged through a 2x8-d LDS buffer.
__global__ __launch_bounds__(256, 2)
void scompute_kernel(const float* __restrict__ zx, const float* __restrict__ zy,
                     float* __restrict__ Sp, float* __restrict__ accum) {
  const int h   = blockIdx.z;
  const int i0  = blockIdx.y * 32;
  const int j0q = blockIdx.x * 64;   // col-quad base (256 cols)
  const int t   = threadIdx.x;
  const int g   = t >> 6;            // row group 0..3 (8 rows)
  const int c   = t & 63;            // col quad within tile
  if (t == 0 && (blockIdx.x | blockIdx.y | blockIdx.z) == 0) {
    accum[0] = 0.f; accum[1] = 0.f; ((unsigned int*)accum)[2] = 0u;
  }

  __shared__ float  xs[CH][32];      // 8 KB: xs[d][r]
  __shared__ float4 ys[2][8][64];    // 16 KB: double-buffered 8-d y chunks

  // stage x slab: CH*32 floats = 512 float4, 2 per thread (coalesced)
  {
    const float4* __restrict__ X4 = (const float4*)zx;
    float4* xs4 = (float4*)xs;
    #pragma unroll
    for (int k = t; k < CH * 8; k += 256)
      xs4[k] = X4[(h * CH + (k >> 3)) * NQ + (i0 >> 2) + (k & 7)];
  }

  const float4* __restrict__ Y4 = (const float4*)zy + (size_t)(h * CH) * NQ + j0q;
  const int sd0 = t >> 6;            // staging d-offset for first load (0..3)
  const int sd1 = 4 + sd0;           // second load (4..7)

  // preload chunk 0 into buffer 0
  ys[0][sd0][c] = Y4[sd0 * NQ + c];
  ys[0][sd1][c] = Y4[sd1 * NQ + c];
  __syncthreads();                   // xs + chunk 0 ready

  float acc[8][4];
  #pragma unroll
  for (int r = 0; r < 8; ++r)
    #pragma unroll
    for (int q = 0; q < 4; ++q) acc[r][q] = 0.f;

  for (int n = 0; n < CH / 8; ++n) {
    const int buf = n & 1;
    float4 p0, p1;
    if (n < CH / 8 - 1) {            // issue next chunk's loads a chunk ahead
      p0 = Y4[(8 * (n + 1) + sd0) * NQ + c];
      p1 = Y4[(8 * (n + 1) + sd1) * NQ + c];
    }
    #pragma unroll
    for (int dd = 0; dd < 8; ++dd) {
      const int d = n * 8 + dd;
      const float4 xa = *(const float4*)&xs[d][g * 8];
      const float4 xb = *(const float4*)&xs[d][g * 8 + 4];
      const float4 yv = ys[buf][dd][c];
      acc[0][0] += fabsf(xa.x - yv.x); acc[0][1] += fabsf(xa.x - yv.y);
      acc[0][2] += fabsf(xa.x - yv.z); acc[0][3] += fabsf(xa.x - yv.w);
      acc[1][0] += fabsf(xa.y - yv.x); acc[1][1] += fabsf(xa.y - yv.y);
      acc[1][2] += fabsf(xa.y - yv.z); acc[1][3] += fabsf(xa.y - yv.w);
      acc[2][0] += fabsf(xa.z - yv.x); acc[2][1] += fabsf(xa.z - yv.y);
      acc[2][2] += fabsf(xa.z - yv.z); acc[2][3] += fabsf(xa.z - yv.w);
      acc[3][0] += fabsf(xa.w - yv.x); acc[3][1] += fabsf(xa.w - yv.y);
      acc[3][2] += fabsf(xa.w - yv.z); acc[3][3] += fabsf(xa.w - yv.w);
      acc[4][0] += fabsf(xb.x - yv.x); acc[4][1] += fabsf(xb.x - yv.y);
      acc[4][2] += fabsf(xb.x - yv.z); acc[4][3] += fabsf(xb.x - yv.w);
      acc[5][0] += fabsf(xb.y - yv.x); acc[5][1] += fabsf(xb.y - yv.y);
      acc[5][2] += fabsf(xb.y - yv.z); acc[5][3] += fabsf(xb.y - yv.w);
      acc[6][0] += fabsf(xb.z - yv.x); acc[6][1] += fabsf(xb.z - yv.y);
      acc[6][2] += fabsf(xb.z - yv.z); acc[6][3] += fabsf(xb.z - yv.w);
      acc[7][0] += fabsf(xb.w - yv.x); acc[7][1] += fabsf(xb.w - yv.y);
      acc[7][2] += fabsf(xb.w - yv.z); acc[7][3] += fabsf(xb.w - yv.w);
    }
    if (n < CH / 8 - 1) {
      ys[buf ^ 1][sd0][c] = p0;
      ys[buf ^ 1][sd1][c] = p1;
    }
    __syncthreads();
  }

  float4* __restrict__ S4 = (float4*)Sp + (size_t)h * (NN * NQ);
  #pragma unroll
  for (int r = 0; r < 8; ++r)
    S4[(i0 + g * 8 + r) * NQ + j0q + c] =
        make_float4(acc[r][0], acc[r][1], acc[r][2], acc[r][3]);
}

// 512 blocks x 2 rows: sum the 4 slabs (write S back to slab0), full row
// max/sumexp, and per-2-row-stripe column partials.
__global__ __launch_bounds__(256)
void rowcolstats_kernel(float* __restrict__ Sp,
                        float* __restrict__ rmax, float* __restrict__ rsum,
                        float* __restrict__ pm, float* __restrict__ ps) {
  __shared__ float red[4];
  const int t = threadIdx.x;
  const int row0 = blockIdx.x * 2;
  float4* S4 = (float4*)Sp;
  float4 p[2];
  #pragma unroll
  for (int r = 0; r < 2; ++r) {
    float4 v = S4[(row0 + r) * NQ + t];
    #pragma unroll
    for (int hh = 1; hh < DS; ++hh) {
      const float4 q = S4[(size_t)hh * (NN * NQ) + (row0 + r) * NQ + t];
      v.x += q.x; v.y += q.y; v.z += q.z; v.w += q.w;
    }
    S4[(row0 + r) * NQ + t] = v;
    p[r] = v;
  }
  #pragma unroll
  for (int r = 0; r < 2; ++r) {
    float m = fmaxf(fmaxf(-p[r].x, -p[r].y), fmaxf(-p[r].z, -p[r].w));
    m = blockMax(m, red);
    float l = __expf(-p[r].x - m) + __expf(-p[r].y - m) +
              __expf(-p[r].z - m) + __expf(-p[r].w - m);
    l = blockSum(l, red);
    if (t == 0) { rmax[row0 + r] = m; rsum[row0 + r] = l; }
  }
  float4 cm = make_float4(-1e30f, -1e30f, -1e30f, -1e30f);
  #pragma unroll
  for (int r = 0; r < 2; ++r) {
    cm.x = fmaxf(cm.x, -p[r].x); cm.y = fmaxf(cm.y, -p[r].y);
    cm.z = fmaxf(cm.z, -p[r].z); cm.w = fmaxf(cm.w, -p[r].w);
  }
  float4 cl = make_float4(0.f, 0.f, 0.f, 0.f);
  #pragma unroll
  for (int r = 0; r < 2; ++r) {
    cl.x += __expf(-p[r].x - cm.x); cl.y += __expf(-p[r].y - cm.y);
    cl.z += __expf(-p[r].z - cm.z); cl.w += __expf(-p[r].w - cm.w);
  }
  ((float4*)pm)[blockIdx.x * NQ + t] = cm;
  ((float4*)ps)[blockIdx.x * NQ + t] = cl;
}

// Merge the NSTRIPE stripe-partials per column. 16 blocks x 64 cols; the 4
// 64-thread groups each fold 128 stripes, then LDS-combine.
__global__ __launch_bounds__(256)
void colcombine_kernel(const float* __restrict__ pm, const float* __restrict__ ps,
                       float* __restrict__ cmax, float* __restrict__ csum) {
  __shared__ float sm[4][64], sl[4][64];
  const int t  = threadIdx.x;
  const int jl = t & 63;
  const int pc = t >> 6;
  const int j  = blockIdx.x * 64 + jl;
  float m = -1e30f;
  #pragma unroll 8
  for (int k = 0; k < NSTRIPE / 4; ++k)
    m = fmaxf(m, pm[(pc * (NSTRIPE / 4) + k) * NN + j]);
  float l = 0.f;
  #pragma unroll 8
  for (int k = 0; k < NSTRIPE / 4; ++k)
    l += __expf(pm[(pc * (NSTRIPE / 4) + k) * NN + j] - m) *
         ps[(pc * (NSTRIPE / 4) + k) * NN + j];
  sm[pc][jl] = m; sl[pc][jl] = l;
  __syncthreads();
  if (pc == 0) {
    float M = fmaxf(fmaxf(sm[0][jl], sm[1][jl]), fmaxf(sm[2][jl], sm[3][jl]));
    float L = sl[0][jl] * __expf(sm[0][jl] - M) + sl[1][jl] * __expf(sm[1][jl] - M) +
              sl[2][jl] * __expf(sm[2][jl] - M) + sl[3][jl] * __expf(sm[3][jl] - M);
    cmax[j] = M; csum[j] = L;
  }
}

// 512 blocks x 2 rows: u = a+b-a*b, reduce, atomic; LAST block divides.
__global__ __launch_bounds__(256)
void final_kernel(const float* __restrict__ Sp,
                  const float* __restrict__ rmax, const float* __restrict__ rsum,
                  const float* __restrict__ cmax, const float* __restrict__ csum,
                  float* __restrict__ accum, float* __restrict__ out) {
  __shared__ float redn[4], redd[4];
  const int t = threadIdx.x;
  const int row0 = blockIdx.x * 2;
  const float4* S4 = (const float4*)Sp;
  const float4 cm = ((const float4*)cmax)[t];
  const float4 cs = ((const float4*)csum)[t];
  float un = 0.f, ud = 0.f;
  #pragma unroll
  for (int r = 0; r < 2; ++r) {
    const int row = row0 + r;
    const float rm = rmax[row];
    const float ri = 1.f / rsum[row];
    const float4 p = S4[row * NQ + t];
    {
      const float s = -p.x;
      const float a = __expf(s - rm) * ri;
      const float b = __expf(s - cm.x) / cs.x;
      const float u = a + b - a * b;
      un += u * s; ud += u;
    }
    {
      const float s = -p.y;
      const float a = __expf(s - rm) * ri;
      const float b = __expf(s - cm.y) / cs.y;
      const float u = a + b - a * b;
      un += u * s; ud += u;
    }
    {
      const float s = -p.z;
      const float a = __expf(s - rm) * ri;
      const float b = __expf(s - cm.z) / cs.z;
      const float u = a + b - a * b;
      un += u * s; ud += u;
    }
    {
      const float s = -p.w;
      const float a = __expf(s - rm) * ri;
      const float b = __expf(s - cm.w) / cs.w;
      const float u = a + b - a * b;
      un += u * s; ud += u;
    }
  }
  un = waveSum(un); ud = waveSum(ud);
  if ((t & 63) == 0) { redn[t >> 6] = un; redd[t >> 6] = ud; }
  __syncthreads();
  if (t == 0) {
    atomicAdd(&accum[0], redn[0] + redn[1] + redn[2] + redn[3]);
    atomicAdd(&accum[1], redd[0] + redd[1] + redd[2] + redd[3]);
    __threadfence();
    unsigned int* cnt = (unsigned int*)accum + 2;
    const unsigned int old = atomicAdd(cnt, 1u);
    if (old == gridDim.x - 1) {
      const float n = atomicAdd(&accum[0], 0.f);
      const float d = atomicAdd(&accum[1], 0.f);
      out[0] = n / d;
    }
  }
}

// ---------------- fallback path (R2, ws >= ~148 KB, proven) ----------------

#define TJ  128
#define NCH (NN / TJ)
#define BLK 256

__global__ __launch_bounds__(BLK)
void stats2_kernel(const float* __restrict__ zx, const float* __restrict__ zy,
                   float* __restrict__ partM, float* __restrict__ partS) {
  const int side = blockIdx.z;
  const float* __restrict__ X = side ? zy : zx;
  const float* __restrict__ Y = side ? zx : zy;
  const int j0 = blockIdx.x * TJ;
  const int i0 = blockIdx.y * 8;
  const int t  = threadIdx.x;
  const int rg = t >> 5;
  const int c  = t & 31;

  __shared__ float xs[8 * DD];
  for (int k = t; k < 8 * DD; k += BLK)
    xs[k] = X[(k >> 3) * NN + i0 + (k & 7)];
  __syncthreads();

  const float4* __restrict__ Y4 = (const float4*)Y;
  const int yb = (j0 >> 2) + c;
  float4 acc = make_float4(0.f, 0.f, 0.f, 0.f);
  #pragma unroll 8
  for (int d = 0; d < DD; ++d) {
    const float4 yv = Y4[d * NQ + yb];
    const float xv = xs[d * 8 + rg];
    acc.x += fabsf(xv - yv.x);
    acc.y += fabsf(xv - yv.y);
    acc.z += fabsf(xv - yv.z);
    acc.w += fabsf(xv - yv.w);
  }

  float m = fmaxf(fmaxf(-acc.x, -acc.y), fmaxf(-acc.z, -acc.w));
  #pragma unroll
  for (int off = 16; off > 0; off >>= 1) m = fmaxf(m, __shfl_xor(m, off, 32));
  float p = __expf(-acc.x - m) + __expf(-acc.y - m) +
            __expf(-acc.z - m) + __expf(-acc.w - m);
  #pragma unroll
  for (int off = 16; off > 0; off >>= 1) p += __shfl_xor(p, off, 32);

  if (c == 0) {
    const int idx = side * (NCH * NN) + blockIdx.x * NN + (i0 + rg);
    partM[idx] = m;
    partS[idx] = p;
  }
}

__global__ __launch_bounds__(BLK)
void combine_kernel(const float* __restrict__ partM, const float* __restrict__ partS,
                    float* __restrict__ rmax, float* __restrict__ rsum,
                    float* __restrict__ cmax, float* __restrict__ csum,
                    float* __restrict__ accum) {
  const int gid = blockIdx.x * BLK + threadIdx.x;
  if (gid == 0) { accum[0] = 0.f; accum[1] = 0.f; }
  const int sd = gid >> 10;
  const int i  = gid & (NN - 1);
  float mk[NCH], sk[NCH];
  #pragma unroll
  for (int k = 0; k < NCH; ++k) {
    mk[k] = partM[sd * (NCH * NN) + k * NN + i];
    sk[k] = partS[sd * (NCH * NN) + k * NN + i];
  }
  float m = mk[0];
  #pragma unroll
  for (int k = 1; k < NCH; ++k) m = fmaxf(m, mk[k]);
  float s = 0.f;
  #pragma unroll
  for (int k = 0; k < NCH; ++k) s += __expf(mk[k] - m) * sk[k];
  if (sd == 0) { rmax[i] = m; rsum[i] = s; }
  else         { cmax[i] = m; csum[i] = s; }
}

__global__ __launch_bounds__(BLK)
void final2_kernel(const float* __restrict__ zx, const float* __restrict__ zy,
                   const float* __restrict__ rmax, const float* __restrict__ rsum,
                   const float* __restrict__ cmax, const float* __restrict__ csum,
                   float* __restrict__ accum) {
  const int j0 = blockIdx.x * TJ;
  const int i0 = blockIdx.y * 8;
  const int t  = threadIdx.x;
  const int rg = t >> 5;
  const int c  = t & 31;

  __shared__ float xs[8 * DD];
  __shared__ float redn[4], redd[4];
  for (int k = t; k < 8 * DD; k += BLK)
    xs[k] = zx[(k >> 3) * NN + i0 + (k & 7)];
  __syncthreads();

  const float4* __restrict__ Y4 = (const float4*)zy;
  const int yb = (j0 >> 2) + c;
  float4 acc = make_float4(0.f, 0.f, 0.f, 0.f);
  #pragma unroll 8
  for (int d = 0; d < DD; ++d) {
    const float4 yv = Y4[d * NQ + yb];
    const float xv = xs[d * 8 + rg];
    acc.x += fabsf(xv - yv.x);
    acc.y += fabsf(xv - yv.y);
    acc.z += fabsf(xv - yv.z);
    acc.w += fabsf(xv - yv.w);
  }

  const int i = i0 + rg;
  const float rm = rmax[i];
  const float ri = 1.f / rsum[i];
  const float4 cm = ((const float4*)cmax)[yb];
  const float4 cs = ((const float4*)csum)[yb];

  float un = 0.f, ud = 0.f;
  {
    const float s = -acc.x;
    const float a = __expf(s - rm) * ri;
    const float b = __expf(s - cm.x) / cs.x;
    const float u = a + b - a * b;
    un += u * s; ud += u;
  }
  {
    const float s = -acc.y;
    const float a = __expf(s - rm) * ri;
    const float b = __expf(s - cm.y) / cs.y;
    const float u = a + b - a * b;
    un += u * s; ud += u;
  }
  {
    const float s = -acc.z;
    const float a = __expf(s - rm) * ri;
    const float b = __expf(s - cm.z) / cs.z;
    const float u = a + b - a * b;
    un += u * s; ud += u;
  }
  {
    const float s = -acc.w;
    const float a = __expf(s - rm) * ri;
    const float b = __expf(s - cm.w) / cs.w;
    const float u = a + b - a * b;
    un += u * s; ud += u;
  }

  un = waveSum(un); ud = waveSum(ud);
  if ((t & 63) == 0) { redn[t >> 6] = un; redd[t >> 6] = ud; }
  __syncthreads();
  if (t == 0) {
    atomicAdd(&accum[0], redn[0] + redn[1] + redn[2] + redn[3]);
    atomicAdd(&accum[1], redd[0] + redd[1] + redd[2] + redd[3]);
  }
}

__global__ void finalize_kernel(const float* __restrict__ accum, float* __restrict__ out) {
  out[0] = accum[0] / accum[1];
}

// ---------------------------------------------------------------------------

extern "C" void kernel_launch(void* const* d_in, const int* in_sizes, int n_in,
                              void* d_out, int out_size, void* d_ws, size_t ws_size,
                              hipStream_t stream) {
  const float* zx = (const float*)d_in[0];   // (1, D, N): X[d*N + i]
  const float* zy = (const float*)d_in[1];   // (1, D, M): Y[d*M + j]
  float* ws  = (float*)d_ws;
  float* out = (float*)d_out;

  // fast-path ws layout (floats)
  float* accum = ws;                         // [0]=num, [1]=den, [2]=ticket
  float* Sp    = ws + 16;                    // DS * 1M
  float* pm    = Sp + DS * NN * NN;          // NSTRIPE*1024
  float* ps    = pm + NSTRIPE * NN;          // NSTRIPE*1024
  float* rmax  = ps + NSTRIPE * NN;
  float* rsum  = rmax + NN;
  float* cmax  = rsum + NN;
  float* csum  = cmax + NN;
  const size_t need = (size_t)((csum + NN) - ws) * sizeof(float);  // ~21 MB

  if (ws_size >= need) {
    dim3 g1(NN / 256, NN / 32, DS);          // 512 blocks
    scompute_kernel<<<g1, 256, 0, stream>>>(zx, zy, Sp, accum);
    rowcolstats_kernel<<<NSTRIPE, 256, 0, stream>>>(Sp, rmax, rsum, pm, ps);
    colcombine_kernel<<<NN / 64, 256, 0, stream>>>(pm, ps, cmax, csum);
    final_kernel<<<NN / 2, 256, 0, stream>>>(Sp, rmax, rsum, cmax, csum, accum, out);
  } else {
    // R2 fallback (~148 KB)
    float* partM = ws + 16;
    float* partS = partM + 2 * NCH * NN;
    float* frmax = partS + 2 * NCH * NN;
    float* frsum = frmax + NN;
    float* fcmax = frsum + NN;
    float* fcsum = fcmax + NN;
    dim3 sgrid(NCH, NN / 8, 2);
    stats2_kernel<<<sgrid, BLK, 0, stream>>>(zx, zy, partM, partS);
    combine_kernel<<<(2 * NN) / BLK, BLK, 0, stream>>>(partM, partS,
                                                       frmax, frsum, fcmax, fcsum, accum);
    dim3 fgrid(NCH, NN / 8);
    final2_kernel<<<fgrid, BLK, 0, stream>>>(zx, zy, frmax, frsum, fcmax, fcsum, accum);
    finalize_kernel<<<1, 1, 0, stream>>>(accum, out);
  }
}

// Round 6
// 127.810 us; speedup vs baseline: 1.0818x; 1.0818x over previous
//
#include <hip/hip_runtime.h>
#include <math.h>

// SSAaligner: s[i,j] = -sum_d |x[i,d]-y[j,d]|, x from z_x(D,N), y from z_y(D,M)
// a = softmax_rows(s), b = softmax_cols(s), u = a+b-a*b, out = sum(u*s)/sum(u)
// D=256, N=M=1024. fp32 in, fp32 scalar out.
//
// R6: full-d scompute (tile 16x256, thread 4rx4c, y LDS-double-buffered,
// x LDS-broadcast) fuses S-write + row-stat partials + col-stat partials into
// ONE distance pass. No d-split slabs, no slab-sum pass, no separate stats
// passes. 3 kernels total: scompute -> combine -> final(ticket-divide).
// ~44 us of the measured total is the harness's 268 MB ws poison fill.

#define DD 256
#define NN 1024
#define NQ 256         // float4 per row

__device__ __forceinline__ float waveMax(float v) {
  #pragma unroll
  for (int off = 32; off; off >>= 1) v = fmaxf(v, __shfl_xor(v, off, 64));
  return v;
}
__device__ __forceinline__ float waveSum(float v) {
  #pragma unroll
  for (int off = 32; off; off >>= 1) v += __shfl_xor(v, off, 64);
  return v;
}

// ---------------- fast path ----------------

// Grid (4 j-chunks, 64 i-tiles) = 256 blocks. Block: 256 threads, tile
// 16 rows x 256 cols x full 256 d. Thread: 4 rows x 4 cols (16 acc).
// Wave w owns rows i0+4w..i0+4w+3 (x reads are wave-uniform LDS broadcasts);
// lane owns col-quad j0+4*lane.
__global__ __launch_bounds__(256, 1)
void scompute_kernel(const float* __restrict__ zx, const float* __restrict__ zy,
                     float* __restrict__ S,
                     float* __restrict__ pRM, float* __restrict__ pRL,
                     float* __restrict__ pCM, float* __restrict__ pCL) {
  const int bx = blockIdx.x;        // j-chunk 0..3 (256 cols each)
  const int by = blockIdx.y;        // i-tile 0..63 (16 rows each)
  const int i0 = by * 16;
  const int t  = threadIdx.x;
  const int w  = t >> 6;            // wave / row-group 0..3
  const int ln = t & 63;            // lane / col-quad

  __shared__ float xs[DD][16];      // 16 KB, xs[d][r] — wave-uniform reads
  __shared__ float ys[2][8][256];   // 16 KB, double-buffered 8-d y chunks
  __shared__ float cmS[4][256];     // 4 KB col-partial max per row-group
  __shared__ float clS[4][256];     // 4 KB col-partial sum per row-group

  const float4* __restrict__ X4 = (const float4*)zx;
  const float4* __restrict__ Y4 = (const float4*)zy;

  // stage x tile once: 256 d x 16 rows = 1024 float4, 4 per thread
  #pragma unroll
  for (int i = 0; i < 4; ++i) {
    const int k = t + i * 256;
    const int d = k >> 2, rq = k & 3;
    *(float4*)&xs[d][rq * 4] = X4[d * NQ + by * 4 + rq];
  }

  // stage y chunk 0: 8 d x 64 quads = 512 float4, 2 per thread
  const int sd = t >> 6;            // 0..3
  const int sq = t & 63;
  {
    const float4 q0 = Y4[(sd)     * NQ + bx * 64 + sq];
    const float4 q1 = Y4[(4 + sd) * NQ + bx * 64 + sq];
    *(float4*)&ys[0][sd][sq * 4]     = q0;
    *(float4*)&ys[0][4 + sd][sq * 4] = q1;
  }
  __syncthreads();

  float acc[4][4];
  #pragma unroll
  for (int r = 0; r < 4; ++r)
    #pragma unroll
    for (int c = 0; c < 4; ++c) acc[r][c] = 0.f;

  #pragma unroll 1
  for (int n = 0; n < DD / 8; ++n) {
    const int buf = n & 1;
    float4 p0, p1;
    if (n < DD / 8 - 1) {           // prefetch next chunk (global), used after compute
      p0 = Y4[(8 * (n + 1) + sd)     * NQ + bx * 64 + sq];
      p1 = Y4[(8 * (n + 1) + 4 + sd) * NQ + bx * 64 + sq];
    }
    #pragma unroll
    for (int dd = 0; dd < 8; ++dd) {
      const int d = n * 8 + dd;
      const float4 xv = *(const float4*)&xs[d][w * 4];
      const float4 yv = *(const float4*)&ys[buf][dd][ln * 4];
      acc[0][0] += fabsf(xv.x - yv.x); acc[0][1] += fabsf(xv.x - yv.y);
      acc[0][2] += fabsf(xv.x - yv.z); acc[0][3] += fabsf(xv.x - yv.w);
      acc[1][0] += fabsf(xv.y - yv.x); acc[1][1] += fabsf(xv.y - yv.y);
      acc[1][2] += fabsf(xv.y - yv.z); acc[1][3] += fabsf(xv.y - yv.w);
      acc[2][0] += fabsf(xv.z - yv.x); acc[2][1] += fabsf(xv.z - yv.y);
      acc[2][2] += fabsf(xv.z - yv.z); acc[2][3] += fabsf(xv.z - yv.w);
      acc[3][0] += fabsf(xv.w - yv.x); acc[3][1] += fabsf(xv.w - yv.y);
      acc[3][2] += fabsf(xv.w - yv.z); acc[3][3] += fabsf(xv.w - yv.w);
    }
    if (n < DD / 8 - 1) {
      *(float4*)&ys[buf ^ 1][sd][sq * 4]     = p0;
      *(float4*)&ys[buf ^ 1][4 + sd][sq * 4] = p1;
    }
    __syncthreads();
  }

  // ---- epilogue ----
  // S write: 4 rows x float4, coalesced
  float4* __restrict__ S4 = (float4*)S;
  #pragma unroll
  for (int r = 0; r < 4; ++r)
    S4[(i0 + w * 4 + r) * NQ + bx * 64 + ln] =
        make_float4(acc[r][0], acc[r][1], acc[r][2], acc[r][3]);

  // row-stat partials over this 256-col chunk (wave-wide: rows are per-wave)
  #pragma unroll
  for (int r = 0; r < 4; ++r) {
    float m = fmaxf(fmaxf(-acc[r][0], -acc[r][1]), fmaxf(-acc[r][2], -acc[r][3]));
    m = waveMax(m);
    float l = __expf(-acc[r][0] - m) + __expf(-acc[r][1] - m) +
              __expf(-acc[r][2] - m) + __expf(-acc[r][3] - m);
    l = waveSum(l);
    if (ln == 0) {
      pRM[bx * NN + i0 + w * 4 + r] = m;
      pRL[bx * NN + i0 + w * 4 + r] = l;
    }
  }

  // col-stat partials over this 16-row tile: thread-local over 4 rows,
  // then merge the 4 row-groups via LDS
  #pragma unroll
  for (int c = 0; c < 4; ++c) {
    float m = fmaxf(fmaxf(-acc[0][c], -acc[1][c]), fmaxf(-acc[2][c], -acc[3][c]));
    float l = __expf(-acc[0][c] - m) + __expf(-acc[1][c] - m) +
              __expf(-acc[2][c] - m) + __expf(-acc[3][c] - m);
    cmS[w][ln * 4 + c] = m;
    clS[w][ln * 4 + c] = l;
  }
  __syncthreads();
  {
    const int j = t;   // 256 local cols, one per thread
    const float m0 = cmS[0][j], m1 = cmS[1][j], m2 = cmS[2][j], m3 = cmS[3][j];
    const float M = fmaxf(fmaxf(m0, m1), fmaxf(m2, m3));
    const float L = clS[0][j] * __expf(m0 - M) + clS[1][j] * __expf(m1 - M) +
                    clS[2][j] * __expf(m2 - M) + clS[3][j] * __expf(m3 - M);
    pCM[by * NN + bx * 256 + j] = M;
    pCL[by * NN + bx * 256 + j] = L;
  }
}

// 8 blocks x 256: blocks 0..3 fold the 4 row-chunk partials per row,
// blocks 4..7 fold the 64 i-tile partials per column.
__global__ __launch_bounds__(256)
void combine_kernel(const float* __restrict__ pRM, const float* __restrict__ pRL,
                    const float* __restrict__ pCM, const float* __restrict__ pCL,
                    float* __restrict__ rmax, float* __restrict__ rsum,
                    float* __restrict__ cmax, float* __restrict__ csum,
                    float* __restrict__ accum) {
  const int b = blockIdx.x, t = threadIdx.x;
  if (b == 0 && t == 0) {
    accum[0] = 0.f; accum[1] = 0.f; ((unsigned int*)accum)[2] = 0u;
  }
  if (b < 4) {
    const int r = b * 256 + t;
    float mk[4], lk[4];
    #pragma unroll
    for (int k = 0; k < 4; ++k) { mk[k] = pRM[k * NN + r]; lk[k] = pRL[k * NN + r]; }
    float m = fmaxf(fmaxf(mk[0], mk[1]), fmaxf(mk[2], mk[3]));
    float l = lk[0] * __expf(mk[0] - m) + lk[1] * __expf(mk[1] - m) +
              lk[2] * __expf(mk[2] - m) + lk[3] * __expf(mk[3] - m);
    rmax[r] = m; rsum[r] = l;
  } else {
    const int j = (b - 4) * 256 + t;
    float m = -1e30f;
    #pragma unroll 8
    for (int k = 0; k < 64; ++k) m = fmaxf(m, pCM[k * NN + j]);
    float l = 0.f;
    #pragma unroll 8
    for (int k = 0; k < 64; ++k) l += __expf(pCM[k * NN + j] - m) * pCL[k * NN + j];
    cmax[j] = m; csum[j] = l;
  }
}

// 512 blocks x 2 rows: u = a+b-a*b, reduce, atomic; LAST block divides.
__global__ __launch_bounds__(256)
void final_kernel(const float* __restrict__ S,
                  const float* __restrict__ rmax, const float* __restrict__ rsum,
                  const float* __restrict__ cmax, const float* __restrict__ csum,
                  float* __restrict__ accum, float* __restrict__ out) {
  __shared__ float redn[4], redd[4];
  const int t = threadIdx.x;
  const int row0 = blockIdx.x * 2;
  const float4* S4 = (const float4*)S;
  const float4 cm = ((const float4*)cmax)[t];
  const float4 cs = ((const float4*)csum)[t];
  float un = 0.f, ud = 0.f;
  #pragma unroll
  for (int r = 0; r < 2; ++r) {
    const int row = row0 + r;
    const float rm = rmax[row];
    const float ri = 1.f / rsum[row];
    const float4 p = S4[row * NQ + t];
    {
      const float s = -p.x;
      const float a = __expf(s - rm) * ri;
      const float b = __expf(s - cm.x) / cs.x;
      const float u = a + b - a * b;
      un += u * s; ud += u;
    }
    {
      const float s = -p.y;
      const float a = __expf(s - rm) * ri;
      const float b = __expf(s - cm.y) / cs.y;
      const float u = a + b - a * b;
      un += u * s; ud += u;
    }
    {
      const float s = -p.z;
      const float a = __expf(s - rm) * ri;
      const float b = __expf(s - cm.z) / cs.z;
      const float u = a + b - a * b;
      un += u * s; ud += u;
    }
    {
      const float s = -p.w;
      const float a = __expf(s - rm) * ri;
      const float b = __expf(s - cm.w) / cs.w;
      const float u = a + b - a * b;
      un += u * s; ud += u;
    }
  }
  un = waveSum(un); ud = waveSum(ud);
  if ((t & 63) == 0) { redn[t >> 6] = un; redd[t >> 6] = ud; }
  __syncthreads();
  if (t == 0) {
    atomicAdd(&accum[0], redn[0] + redn[1] + redn[2] + redn[3]);
    atomicAdd(&accum[1], redd[0] + redd[1] + redd[2] + redd[3]);
    __threadfence();
    unsigned int* cnt = (unsigned int*)accum + 2;
    const unsigned int old = atomicAdd(cnt, 1u);
    if (old == gridDim.x - 1) {
      const float n = atomicAdd(&accum[0], 0.f);
      const float d = atomicAdd(&accum[1], 0.f);
      out[0] = n / d;
    }
  }
}

// ---------------- fallback path (R2, ws >= ~148 KB, proven) ----------------

#define TJ  128
#define NCH (NN / TJ)
#define BLK 256

__global__ __launch_bounds__(BLK)
void stats2_kernel(const float* __restrict__ zx, const float* __restrict__ zy,
                   float* __restrict__ partM, float* __restrict__ partS) {
  const int side = blockIdx.z;
  const float* __restrict__ X = side ? zy : zx;
  const float* __restrict__ Y = side ? zx : zy;
  const int j0 = blockIdx.x * TJ;
  const int i0 = blockIdx.y * 8;
  const int t  = threadIdx.x;
  const int rg = t >> 5;
  const int c  = t & 31;

  __shared__ float xs[8 * DD];
  for (int k = t; k < 8 * DD; k += BLK)
    xs[k] = X[(k >> 3) * NN + i0 + (k & 7)];
  __syncthreads();

  const float4* __restrict__ Y4 = (const float4*)Y;
  const int yb = (j0 >> 2) + c;
  float4 acc = make_float4(0.f, 0.f, 0.f, 0.f);
  #pragma unroll 8
  for (int d = 0; d < DD; ++d) {
    const float4 yv = Y4[d * NQ + yb];
    const float xv = xs[d * 8 + rg];
    acc.x += fabsf(xv - yv.x);
    acc.y += fabsf(xv - yv.y);
    acc.z += fabsf(xv - yv.z);
    acc.w += fabsf(xv - yv.w);
  }

  float m = fmaxf(fmaxf(-acc.x, -acc.y), fmaxf(-acc.z, -acc.w));
  #pragma unroll
  for (int off = 16; off > 0; off >>= 1) m = fmaxf(m, __shfl_xor(m, off, 32));
  float p = __expf(-acc.x - m) + __expf(-acc.y - m) +
            __expf(-acc.z - m) + __expf(-acc.w - m);
  #pragma unroll
  for (int off = 16; off > 0; off >>= 1) p += __shfl_xor(p, off, 32);

  if (c == 0) {
    const int idx = side * (NCH * NN) + blockIdx.x * NN + (i0 + rg);
    partM[idx] = m;
    partS[idx] = p;
  }
}

__global__ __launch_bounds__(BLK)
void combine_kernel_fb(const float* __restrict__ partM, const float* __restrict__ partS,
                       float* __restrict__ rmax, float* __restrict__ rsum,
                       float* __restrict__ cmax, float* __restrict__ csum,
                       float* __restrict__ accum) {
  const int gid = blockIdx.x * BLK + threadIdx.x;
  if (gid == 0) { accum[0] = 0.f; accum[1] = 0.f; }
  const int sd = gid >> 10;
  const int i  = gid & (NN - 1);
  float mk[NCH], sk[NCH];
  #pragma unroll
  for (int k = 0; k < NCH; ++k) {
    mk[k] = partM[sd * (NCH * NN) + k * NN + i];
    sk[k] = partS[sd * (NCH * NN) + k * NN + i];
  }
  float m = mk[0];
  #pragma unroll
  for (int k = 1; k < NCH; ++k) m = fmaxf(m, mk[k]);
  float s = 0.f;
  #pragma unroll
  for (int k = 0; k < NCH; ++k) s += __expf(mk[k] - m) * sk[k];
  if (sd == 0) { rmax[i] = m; rsum[i] = s; }
  else         { cmax[i] = m; csum[i] = s; }
}

__global__ __launch_bounds__(BLK)
void final2_kernel(const float* __restrict__ zx, const float* __restrict__ zy,
                   const float* __restrict__ rmax, const float* __restrict__ rsum,
                   const float* __restrict__ cmax, const float* __restrict__ csum,
                   float* __restrict__ accum) {
  const int j0 = blockIdx.x * TJ;
  const int i0 = blockIdx.y * 8;
  const int t  = threadIdx.x;
  const int rg = t >> 5;
  const int c  = t & 31;

  __shared__ float xs[8 * DD];
  __shared__ float redn[4], redd[4];
  for (int k = t; k < 8 * DD; k += BLK)
    xs[k] = zx[(k >> 3) * NN + i0 + (k & 7)];
  __syncthreads();

  const float4* __restrict__ Y4 = (const float4*)zy;
  const int yb = (j0 >> 2) + c;
  float4 acc = make_float4(0.f, 0.f, 0.f, 0.f);
  #pragma unroll 8
  for (int d = 0; d < DD; ++d) {
    const float4 yv = Y4[d * NQ + yb];
    const float xv = xs[d * 8 + rg];
    acc.x += fabsf(xv - yv.x);
    acc.y += fabsf(xv - yv.y);
    acc.z += fabsf(xv - yv.z);
    acc.w += fabsf(xv - yv.w);
  }

  const int i = i0 + rg;
  const float rm = rmax[i];
  const float ri = 1.f / rsum[i];
  const float4 cm = ((const float4*)cmax)[yb];
  const float4 cs = ((const float4*)csum)[yb];

  float un = 0.f, ud = 0.f;
  {
    const float s = -acc.x;
    const float a = __expf(s - rm) * ri;
    const float b = __expf(s - cm.x) / cs.x;
    const float u = a + b - a * b;
    un += u * s; ud += u;
  }
  {
    const float s = -acc.y;
    const float a = __expf(s - rm) * ri;
    const float b = __expf(s - cm.y) / cs.y;
    const float u = a + b - a * b;
    un += u * s; ud += u;
  }
  {
    const float s = -acc.z;
    const float a = __expf(s - rm) * ri;
    const float b = __expf(s - cm.z) / cs.z;
    const float u = a + b - a * b;
    un += u * s; ud += u;
  }
  {
    const float s = -acc.w;
    const float a = __expf(s - rm) * ri;
    const float b = __expf(s - cm.w) / cs.w;
    const float u = a + b - a * b;
    un += u * s; ud += u;
  }

  un = waveSum(un); ud = waveSum(ud);
  if ((t & 63) == 0) { redn[t >> 6] = un; redd[t >> 6] = ud; }
  __syncthreads();
  if (t == 0) {
    atomicAdd(&accum[0], redn[0] + redn[1] + redn[2] + redn[3]);
    atomicAdd(&accum[1], redd[0] + redd[1] + redd[2] + redd[3]);
  }
}

__global__ void finalize_kernel(const float* __restrict__ accum, float* __restrict__ out) {
  out[0] = accum[0] / accum[1];
}

// ---------------------------------------------------------------------------

extern "C" void kernel_launch(void* const* d_in, const int* in_sizes, int n_in,
                              void* d_out, int out_size, void* d_ws, size_t ws_size,
                              hipStream_t stream) {
  const float* zx = (const float*)d_in[0];   // (1, D, N): X[d*N + i]
  const float* zy = (const float*)d_in[1];   // (1, D, M): Y[d*M + j]
  float* ws  = (float*)d_ws;
  float* out = (float*)d_out;

  // fast-path ws layout (floats): ~4.6 MB
  float* accum = ws;                         // [0]=num, [1]=den, [2]=ticket
  float* S     = ws + 16;                    // 1M floats (4 MB)
  float* pRM   = S + NN * NN;                // 4 * 1024
  float* pRL   = pRM + 4 * NN;
  float* pCM   = pRL + 4 * NN;               // 64 * 1024
  float* pCL   = pCM + 64 * NN;
  float* rmax  = pCL + 64 * NN;
  float* rsum  = rmax + NN;
  float* cmax  = rsum + NN;
  float* csum  = cmax + NN;
  const size_t need = (size_t)((csum + NN) - ws) * sizeof(float);

  if (ws_size >= need) {
    dim3 g1(4, 64);                          // 256 blocks
    scompute_kernel<<<g1, 256, 0, stream>>>(zx, zy, S, pRM, pRL, pCM, pCL);
    combine_kernel<<<8, 256, 0, stream>>>(pRM, pRL, pCM, pCL,
                                          rmax, rsum, cmax, csum, accum);
    final_kernel<<<NN / 2, 256, 0, stream>>>(S, rmax, rsum, cmax, csum, accum, out);
  } else {
    // R2 fallback (~148 KB)
    float* partM = ws + 16;
    float* partS = partM + 2 * NCH * NN;
    float* frmax = partS + 2 * NCH * NN;
    float* frsum = frmax + NN;
    float* fcmax = frsum + NN;
    float* fcsum = fcmax + NN;
    dim3 sgrid(NCH, NN / 8, 2);
    stats2_kernel<<<sgrid, BLK, 0, stream>>>(zx, zy, partM, partS);
    combine_kernel_fb<<<(2 * NN) / BLK, BLK, 0, stream>>>(partM, partS,
                                                          frmax, frsum, fcmax, fcsum, accum);
    dim3 fgrid(NCH, NN / 8);
    final2_kernel<<<fgrid, BLK, 0, stream>>>(zx, zy, frmax, frsum, fcmax, fcsum, accum);
    finalize_kernel<<<1, 1, 0, stream>>>(accum, out);
  }
}

// Round 7
// 121.083 us; speedup vs baseline: 1.1419x; 1.0556x over previous
//
#include <hip/hip_runtime.h>
#include <math.h>

// SSAaligner: s[i,j] = -sum_d |x[i,d]-y[j,d]|, x from z_x(D,N), y from z_y(D,M)
// a = softmax_rows(s), b = softmax_cols(s), u = a+b-a*b, out = sum(u*s)/sum(u)
// D=256, N=M=1024. fp32 in, fp32 scalar out.
//
// R7: R6's fused single-pass structure, but 512 blocks (tile 16x128) so each
// CU holds 2 blocks = 2 waves/SIMD. R6's 256-block grid left 1 wave/SIMD and
// 31% VALUBusy (all LDS/barrier latency exposed). Thread = 4 rows x 2 cols;
// wave owns 4 rows (y-LDS demand 64 B/cyc/CU), x reads are wave-uniform
// broadcasts. ~44 us of measured total is the harness's 268 MB ws-poison fill.

#define DD 256
#define NN 1024
#define NQ 256         // float4 per row

__device__ __forceinline__ float waveMax(float v) {
  #pragma unroll
  for (int off = 32; off; off >>= 1) v = fmaxf(v, __shfl_xor(v, off, 64));
  return v;
}
__device__ __forceinline__ float waveSum(float v) {
  #pragma unroll
  for (int off = 32; off; off >>= 1) v += __shfl_xor(v, off, 64);
  return v;
}

// ---------------- fast path ----------------

// Grid (8 j-chunks, 64 i-tiles) = 512 blocks, 256 threads. Tile 16r x 128c x
// 256d. Wave w owns rows i0+4w..+3; lane ln owns cols j0+2*ln..+1.
__global__ __launch_bounds__(256, 2)
void scompute_kernel(const float* __restrict__ zx, const float* __restrict__ zy,
                     float* __restrict__ S,
                     float* __restrict__ pRM, float* __restrict__ pRL,
                     float* __restrict__ pCM, float* __restrict__ pCL) {
  const int bx = blockIdx.x;        // j-chunk 0..7 (128 cols)
  const int by = blockIdx.y;        // i-tile 0..63 (16 rows)
  const int i0 = by * 16;
  const int t  = threadIdx.x;
  const int w  = t >> 6;            // wave 0..3
  const int ln = t & 63;            // lane

  __shared__ float xs[DD][16];      // 16 KB, xs[d][r] — wave-uniform reads
  __shared__ float ys[2][8][128];   // 8 KB, double-buffered 8-d y chunks
  __shared__ float cmS[4][128];     // 2 KB
  __shared__ float clS[4][128];     // 2 KB

  const float4* __restrict__ X4 = (const float4*)zx;
  const float4* __restrict__ Y4 = (const float4*)zy;

  // stage x tile: 256 d x 4 quads = 1024 float4, 4 per thread
  #pragma unroll
  for (int i = 0; i < 4; ++i) {
    const int k = t + i * 256;
    const int d = k >> 2, rq = k & 3;
    *(float4*)&xs[d][rq * 4] = X4[d * NQ + by * 4 + rq];
  }

  // stage y chunk 0: 8 d x 32 quads = 256 float4, 1 per thread
  const int sd = t >> 5;            // d-row 0..7
  const int sq = t & 31;            // quad 0..31
  const int jq0 = bx * 32;
  *(float4*)&ys[0][sd][sq * 4] = Y4[sd * NQ + jq0 + sq];
  __syncthreads();

  float acc[4][2];
  #pragma unroll
  for (int r = 0; r < 4; ++r) { acc[r][0] = 0.f; acc[r][1] = 0.f; }

  #pragma unroll 1
  for (int n = 0; n < DD / 8; ++n) {
    const int buf = n & 1;
    float4 p0;
    if (n < DD / 8 - 1)
      p0 = Y4[(8 * (n + 1) + sd) * NQ + jq0 + sq];
    #pragma unroll
    for (int dd = 0; dd < 8; ++dd) {
      const int d = n * 8 + dd;
      const float4 xv = *(const float4*)&xs[d][w * 4];
      const float2 yv = *(const float2*)&ys[buf][dd][ln * 2];
      acc[0][0] += fabsf(xv.x - yv.x); acc[0][1] += fabsf(xv.x - yv.y);
      acc[1][0] += fabsf(xv.y - yv.x); acc[1][1] += fabsf(xv.y - yv.y);
      acc[2][0] += fabsf(xv.z - yv.x); acc[2][1] += fabsf(xv.z - yv.y);
      acc[3][0] += fabsf(xv.w - yv.x); acc[3][1] += fabsf(xv.w - yv.y);
    }
    if (n < DD / 8 - 1)
      *(float4*)&ys[buf ^ 1][sd][sq * 4] = p0;
    __syncthreads();
  }

  // ---- epilogue ----
  float2* __restrict__ S2 = (float2*)S;
  #pragma unroll
  for (int r = 0; r < 4; ++r)
    S2[(i0 + w * 4 + r) * (NN / 2) + bx * 64 + ln] = make_float2(acc[r][0], acc[r][1]);

  // row-stat partials over this 128-col chunk (rows are per-wave)
  #pragma unroll
  for (int r = 0; r < 4; ++r) {
    float m = fmaxf(-acc[r][0], -acc[r][1]);
    m = waveMax(m);
    float l = __expf(-acc[r][0] - m) + __expf(-acc[r][1] - m);
    l = waveSum(l);
    if (ln == 0) {
      pRM[bx * NN + i0 + w * 4 + r] = m;
      pRL[bx * NN + i0 + w * 4 + r] = l;
    }
  }

  // col-stat partials over this 16-row tile
  #pragma unroll
  for (int c = 0; c < 2; ++c) {
    float m = fmaxf(fmaxf(-acc[0][c], -acc[1][c]), fmaxf(-acc[2][c], -acc[3][c]));
    float l = __expf(-acc[0][c] - m) + __expf(-acc[1][c] - m) +
              __expf(-acc[2][c] - m) + __expf(-acc[3][c] - m);
    cmS[w][ln * 2 + c] = m;
    clS[w][ln * 2 + c] = l;
  }
  __syncthreads();
  if (t < 128) {
    const int j = t;
    const float m0 = cmS[0][j], m1 = cmS[1][j], m2 = cmS[2][j], m3 = cmS[3][j];
    const float M = fmaxf(fmaxf(m0, m1), fmaxf(m2, m3));
    const float L = clS[0][j] * __expf(m0 - M) + clS[1][j] * __expf(m1 - M) +
                    clS[2][j] * __expf(m2 - M) + clS[3][j] * __expf(m3 - M);
    pCM[by * NN + bx * 128 + j] = M;
    pCL[by * NN + bx * 128 + j] = L;
  }
}

// 8 blocks x 256: blocks 0..3 fold the 8 row-chunk partials per row,
// blocks 4..7 fold the 64 i-tile partials per column.
__global__ __launch_bounds__(256)
void combine_kernel(const float* __restrict__ pRM, const float* __restrict__ pRL,
                    const float* __restrict__ pCM, const float* __restrict__ pCL,
                    float* __restrict__ rmax, float* __restrict__ rsum,
                    float* __restrict__ cmax, float* __restrict__ csum,
                    float* __restrict__ accum) {
  const int b = blockIdx.x, t = threadIdx.x;
  if (b == 0 && t == 0) {
    accum[0] = 0.f; accum[1] = 0.f; ((unsigned int*)accum)[2] = 0u;
  }
  if (b < 4) {
    const int r = b * 256 + t;
    float mk[8], lk[8];
    #pragma unroll
    for (int k = 0; k < 8; ++k) { mk[k] = pRM[k * NN + r]; lk[k] = pRL[k * NN + r]; }
    float m = mk[0];
    #pragma unroll
    for (int k = 1; k < 8; ++k) m = fmaxf(m, mk[k]);
    float l = 0.f;
    #pragma unroll
    for (int k = 0; k < 8; ++k) l += lk[k] * __expf(mk[k] - m);
    rmax[r] = m; rsum[r] = l;
  } else {
    const int j = (b - 4) * 256 + t;
    float m = -1e30f;
    #pragma unroll 8
    for (int k = 0; k < 64; ++k) m = fmaxf(m, pCM[k * NN + j]);
    float l = 0.f;
    #pragma unroll 8
    for (int k = 0; k < 64; ++k) l += __expf(pCM[k * NN + j] - m) * pCL[k * NN + j];
    cmax[j] = m; csum[j] = l;
  }
}

// 512 blocks x 2 rows: u = a+b-a*b, reduce, atomic; LAST block divides.
__global__ __launch_bounds__(256)
void final_kernel(const float* __restrict__ S,
                  const float* __restrict__ rmax, const float* __restrict__ rsum,
                  const float* __restrict__ cmax, const float* __restrict__ csum,
                  float* __restrict__ accum, float* __restrict__ out) {
  __shared__ float redn[4], redd[4];
  const int t = threadIdx.x;
  const int row0 = blockIdx.x * 2;
  const float4* S4 = (const float4*)S;
  const float4 cm = ((const float4*)cmax)[t];
  const float4 cs = ((const float4*)csum)[t];
  float un = 0.f, ud = 0.f;
  #pragma unroll
  for (int r = 0; r < 2; ++r) {
    const int row = row0 + r;
    const float rm = rmax[row];
    const float ri = 1.f / rsum[row];
    const float4 p = S4[row * NQ + t];
    {
      const float s = -p.x;
      const float a = __expf(s - rm) * ri;
      const float b = __expf(s - cm.x) / cs.x;
      const float u = a + b - a * b;
      un += u * s; ud += u;
    }
    {
      const float s = -p.y;
      const float a = __expf(s - rm) * ri;
      const float b = __expf(s - cm.y) / cs.y;
      const float u = a + b - a * b;
      un += u * s; ud += u;
    }
    {
      const float s = -p.z;
      const float a = __expf(s - rm) * ri;
      const float b = __expf(s - cm.z) / cs.z;
      const float u = a + b - a * b;
      un += u * s; ud += u;
    }
    {
      const float s = -p.w;
      const float a = __expf(s - rm) * ri;
      const float b = __expf(s - cm.w) / cs.w;
      const float u = a + b - a * b;
      un += u * s; ud += u;
    }
  }
  un = waveSum(un); ud = waveSum(ud);
  if ((t & 63) == 0) { redn[t >> 6] = un; redd[t >> 6] = ud; }
  __syncthreads();
  if (t == 0) {
    atomicAdd(&accum[0], redn[0] + redn[1] + redn[2] + redn[3]);
    atomicAdd(&accum[1], redd[0] + redd[1] + redd[2] + redd[3]);
    __threadfence();
    unsigned int* cnt = (unsigned int*)accum + 2;
    const unsigned int old = atomicAdd(cnt, 1u);
    if (old == gridDim.x - 1) {
      const float n = atomicAdd(&accum[0], 0.f);
      const float d = atomicAdd(&accum[1], 0.f);
      out[0] = n / d;
    }
  }
}

// ---------------- fallback path (R2, ws >= ~148 KB, proven) ----------------

#define TJ  128
#define NCH (NN / TJ)
#define BLK 256

__global__ __launch_bounds__(BLK)
void stats2_kernel(const float* __restrict__ zx, const float* __restrict__ zy,
                   float* __restrict__ partM, float* __restrict__ partS) {
  const int side = blockIdx.z;
  const float* __restrict__ X = side ? zy : zx;
  const float* __restrict__ Y = side ? zx : zy;
  const int j0 = blockIdx.x * TJ;
  const int i0 = blockIdx.y * 8;
  const int t  = threadIdx.x;
  const int rg = t >> 5;
  const int c  = t & 31;

  __shared__ float xs[8 * DD];
  for (int k = t; k < 8 * DD; k += BLK)
    xs[k] = X[(k >> 3) * NN + i0 + (k & 7)];
  __syncthreads();

  const float4* __restrict__ Y4 = (const float4*)Y;
  const int yb = (j0 >> 2) + c;
  float4 acc = make_float4(0.f, 0.f, 0.f, 0.f);
  #pragma unroll 8
  for (int d = 0; d < DD; ++d) {
    const float4 yv = Y4[d * NQ + yb];
    const float xv = xs[d * 8 + rg];
    acc.x += fabsf(xv - yv.x);
    acc.y += fabsf(xv - yv.y);
    acc.z += fabsf(xv - yv.z);
    acc.w += fabsf(xv - yv.w);
  }

  float m = fmaxf(fmaxf(-acc.x, -acc.y), fmaxf(-acc.z, -acc.w));
  #pragma unroll
  for (int off = 16; off > 0; off >>= 1) m = fmaxf(m, __shfl_xor(m, off, 32));
  float p = __expf(-acc.x - m) + __expf(-acc.y - m) +
            __expf(-acc.z - m) + __expf(-acc.w - m);
  #pragma unroll
  for (int off = 16; off > 0; off >>= 1) p += __shfl_xor(p, off, 32);

  if (c == 0) {
    const int idx = side * (NCH * NN) + blockIdx.x * NN + (i0 + rg);
    partM[idx] = m;
    partS[idx] = p;
  }
}

__global__ __launch_bounds__(BLK)
void combine_kernel_fb(const float* __restrict__ partM, const float* __restrict__ partS,
                       float* __restrict__ rmax, float* __restrict__ rsum,
                       float* __restrict__ cmax, float* __restrict__ csum,
                       float* __restrict__ accum) {
  const int gid = blockIdx.x * BLK + threadIdx.x;
  if (gid == 0) { accum[0] = 0.f; accum[1] = 0.f; }
  const int sd = gid >> 10;
  const int i  = gid & (NN - 1);
  float mk[NCH], sk[NCH];
  #pragma unroll
  for (int k = 0; k < NCH; ++k) {
    mk[k] = partM[sd * (NCH * NN) + k * NN + i];
    sk[k] = partS[sd * (NCH * NN) + k * NN + i];
  }
  float m = mk[0];
  #pragma unroll
  for (int k = 1; k < NCH; ++k) m = fmaxf(m, mk[k]);
  float s = 0.f;
  #pragma unroll
  for (int k = 0; k < NCH; ++k) s += __expf(mk[k] - m) * sk[k];
  if (sd == 0) { rmax[i] = m; rsum[i] = s; }
  else         { cmax[i] = m; csum[i] = s; }
}

__global__ __launch_bounds__(BLK)
void final2_kernel(const float* __restrict__ zx, const float* __restrict__ zy,
                   const float* __restrict__ rmax, const float* __restrict__ rsum,
                   const float* __restrict__ cmax, const float* __restrict__ csum,
                   float* __restrict__ accum) {
  const int j0 = blockIdx.x * TJ;
  const int i0 = blockIdx.y * 8;
  const int t  = threadIdx.x;
  const int rg = t >> 5;
  const int c  = t & 31;

  __shared__ float xs[8 * DD];
  __shared__ float redn[4], redd[4];
  for (int k = t; k < 8 * DD; k += BLK)
    xs[k] = zx[(k >> 3) * NN + i0 + (k & 7)];
  __syncthreads();

  const float4* __restrict__ Y4 = (const float4*)zy;
  const int yb = (j0 >> 2) + c;
  float4 acc = make_float4(0.f, 0.f, 0.f, 0.f);
  #pragma unroll 8
  for (int d = 0; d < DD; ++d) {
    const float4 yv = Y4[d * NQ + yb];
    const float xv = xs[d * 8 + rg];
    acc.x += fabsf(xv - yv.x);
    acc.y += fabsf(xv - yv.y);
    acc.z += fabsf(xv - yv.z);
    acc.w += fabsf(xv - yv.w);
  }

  const int i = i0 + rg;
  const float rm = rmax[i];
  const float ri = 1.f / rsum[i];
  const float4 cm = ((const float4*)cmax)[yb];
  const float4 cs = ((const float4*)csum)[yb];

  float un = 0.f, ud = 0.f;
  {
    const float s = -acc.x;
    const float a = __expf(s - rm) * ri;
    const float b = __expf(s - cm.x) / cs.x;
    const float u = a + b - a * b;
    un += u * s; ud += u;
  }
  {
    const float s = -acc.y;
    const float a = __expf(s - rm) * ri;
    const float b = __expf(s - cm.y) / cs.y;
    const float u = a + b - a * b;
    un += u * s; ud += u;
  }
  {
    const float s = -acc.z;
    const float a = __expf(s - rm) * ri;
    const float b = __expf(s - cm.z) / cs.z;
    const float u = a + b - a * b;
    un += u * s; ud += u;
  }
  {
    const float s = -acc.w;
    const float a = __expf(s - rm) * ri;
    const float b = __expf(s - cm.w) / cs.w;
    const float u = a + b - a * b;
    un += u * s; ud += u;
  }

  un = waveSum(un); ud = waveSum(ud);
  if ((t & 63) == 0) { redn[t >> 6] = un; redd[t >> 6] = ud; }
  __syncthreads();
  if (t == 0) {
    atomicAdd(&accum[0], redn[0] + redn[1] + redn[2] + redn[3]);
    atomicAdd(&accum[1], redd[0] + redd[1] + redd[2] + redd[3]);
  }
}

__global__ void finalize_kernel(const float* __restrict__ accum, float* __restrict__ out) {
  out[0] = accum[0] / accum[1];
}

// ---------------------------------------------------------------------------

extern "C" void kernel_launch(void* const* d_in, const int* in_sizes, int n_in,
                              void* d_out, int out_size, void* d_ws, size_t ws_size,
                              hipStream_t stream) {
  const float* zx = (const float*)d_in[0];   // (1, D, N): X[d*N + i]
  const float* zy = (const float*)d_in[1];   // (1, D, M): Y[d*M + j]
  float* ws  = (float*)d_ws;
  float* out = (float*)d_out;

  // fast-path ws layout (floats): ~4.8 MB
  float* accum = ws;                         // [0]=num, [1]=den, [2]=ticket
  float* S     = ws + 16;                    // 1M floats (4 MB)
  float* pRM   = S + NN * NN;                // 8 * 1024
  float* pRL   = pRM + 8 * NN;
  float* pCM   = pRL + 8 * NN;               // 64 * 1024
  float* pCL   = pCM + 64 * NN;
  float* rmax  = pCL + 64 * NN;
  float* rsum  = rmax + NN;
  float* cmax  = rsum + NN;
  float* csum  = cmax + NN;
  const size_t need = (size_t)((csum + NN) - ws) * sizeof(float);

  if (ws_size >= need) {
    dim3 g1(8, 64);                          // 512 blocks
    scompute_kernel<<<g1, 256, 0, stream>>>(zx, zy, S, pRM, pRL, pCM, pCL);
    combine_kernel<<<8, 256, 0, stream>>>(pRM, pRL, pCM, pCL,
                                          rmax, rsum, cmax, csum, accum);
    final_kernel<<<NN / 2, 256, 0, stream>>>(S, rmax, rsum, cmax, csum, accum, out);
  } else {
    // R2 fallback (~148 KB)
    float* partM = ws + 16;
    float* partS = partM + 2 * NCH * NN;
    float* frmax = partS + 2 * NCH * NN;
    float* frsum = frmax + NN;
    float* fcmax = frsum + NN;
    float* fcsum = fcmax + NN;
    dim3 sgrid(NCH, NN / 8, 2);
    stats2_kernel<<<sgrid, BLK, 0, stream>>>(zx, zy, partM, partS);
    combine_kernel_fb<<<(2 * NN) / BLK, BLK, 0, stream>>>(partM, partS,
                                                          frmax, frsum, fcmax, fcsum, accum);
    dim3 fgrid(NCH, NN / 8);
    final2_kernel<<<fgrid, BLK, 0, stream>>>(zx, zy, frmax, frsum, fcmax, fcsum, accum);
    finalize_kernel<<<1, 1, 0, stream>>>(accum, out);
  }
}

// Round 8
// 105.530 us; speedup vs baseline: 1.3102x; 1.1474x over previous
//
#include <hip/hip_runtime.h>
#include <math.h>

// SSAaligner: s[i,j] = -sum_d |x[i,d]-y[j,d]|, x from z_x(D,N), y from z_y(D,M)
// a = softmax_rows(s), b = softmax_cols(s), u = a+b-a*b, out = sum(u*s)/sum(u)
// D=256, N=M=1024. fp32 in, fp32 scalar out.
//
// R8: (1) combine widened 8 -> 20 blocks (the old 8-block fold was a
// latency-bound tail, suspected ~25-30 us hidden under the rocprof top-5
// fills); (2) scompute barriers halved via 16-d chunks. scompute itself is
// ~2.4x LDS-issue-bound (x-broadcast b128 + y b64 per wave per d vs 64 cyc
// VALU) -- structural, attacked next round. ~40 us of total is the harness's
// 268 MB ws-poison fill.

#define DD 256
#define NN 1024
#define NQ 256         // float4 per row

__device__ __forceinline__ float waveMax(float v) {
  #pragma unroll
  for (int off = 32; off; off >>= 1) v = fmaxf(v, __shfl_xor(v, off, 64));
  return v;
}
__device__ __forceinline__ float waveSum(float v) {
  #pragma unroll
  for (int off = 32; off; off >>= 1) v += __shfl_xor(v, off, 64);
  return v;
}

// ---------------- fast path ----------------

// Grid (8 j-chunks, 64 i-tiles) = 512 blocks, 256 threads, 2 blocks/CU.
// Tile 16r x 128c x 256d. Wave w owns rows i0+4w..+3; lane ln cols j0+2ln..+1.
// y double-buffered in 16-d LDS chunks (16 barriers total).
__global__ __launch_bounds__(256, 2)
void scompute_kernel(const float* __restrict__ zx, const float* __restrict__ zy,
                     float* __restrict__ S,
                     float* __restrict__ pRM, float* __restrict__ pRL,
                     float* __restrict__ pCM, float* __restrict__ pCL) {
  const int bx = blockIdx.x;        // j-chunk 0..7 (128 cols)
  const int by = blockIdx.y;        // i-tile 0..63 (16 rows)
  const int i0 = by * 16;
  const int t  = threadIdx.x;
  const int w  = t >> 6;            // wave 0..3
  const int ln = t & 63;            // lane

  __shared__ float xs[DD][16];      // 16 KB, xs[d][r] — wave-uniform reads
  __shared__ float ys[2][16][128];  // 16 KB, double-buffered 16-d y chunks
  __shared__ float cmS[4][128];     // 2 KB
  __shared__ float clS[4][128];     // 2 KB

  const float4* __restrict__ X4 = (const float4*)zx;
  const float4* __restrict__ Y4 = (const float4*)zy;

  // stage x tile: 256 d x 4 quads = 1024 float4, 4 per thread
  #pragma unroll
  for (int i = 0; i < 4; ++i) {
    const int k = t + i * 256;
    const int d = k >> 2, rq = k & 3;
    *(float4*)&xs[d][rq * 4] = X4[d * NQ + by * 4 + rq];
  }

  // stage y chunk 0: 16 d x 32 quads = 512 float4, 2 per thread
  const int sd = t >> 4;            // d-row 0..15
  const int sq = t & 15;            // quad 0..15 (plus sq+16)
  const int jq0 = bx * 32;
  *(float4*)&ys[0][sd][sq * 4]        = Y4[sd * NQ + jq0 + sq];
  *(float4*)&ys[0][sd][(sq + 16) * 4] = Y4[sd * NQ + jq0 + sq + 16];
  __syncthreads();

  float acc[4][2];
  #pragma unroll
  for (int r = 0; r < 4; ++r) { acc[r][0] = 0.f; acc[r][1] = 0.f; }

  #pragma unroll 1
  for (int n = 0; n < DD / 16; ++n) {
    const int buf = n & 1;
    float4 p0, p1;
    if (n < DD / 16 - 1) {
      p0 = Y4[(16 * (n + 1) + sd) * NQ + jq0 + sq];
      p1 = Y4[(16 * (n + 1) + sd) * NQ + jq0 + sq + 16];
    }
    #pragma unroll
    for (int dd = 0; dd < 16; ++dd) {
      const int d = n * 16 + dd;
      const float4 xv = *(const float4*)&xs[d][w * 4];
      const float2 yv = *(const float2*)&ys[buf][dd][ln * 2];
      acc[0][0] += fabsf(xv.x - yv.x); acc[0][1] += fabsf(xv.x - yv.y);
      acc[1][0] += fabsf(xv.y - yv.x); acc[1][1] += fabsf(xv.y - yv.y);
      acc[2][0] += fabsf(xv.z - yv.x); acc[2][1] += fabsf(xv.z - yv.y);
      acc[3][0] += fabsf(xv.w - yv.x); acc[3][1] += fabsf(xv.w - yv.y);
    }
    if (n < DD / 16 - 1) {
      *(float4*)&ys[buf ^ 1][sd][sq * 4]        = p0;
      *(float4*)&ys[buf ^ 1][sd][(sq + 16) * 4] = p1;
    }
    __syncthreads();
  }

  // ---- epilogue ----
  float2* __restrict__ S2 = (float2*)S;
  #pragma unroll
  for (int r = 0; r < 4; ++r)
    S2[(i0 + w * 4 + r) * (NN / 2) + bx * 64 + ln] = make_float2(acc[r][0], acc[r][1]);

  // row-stat partials over this 128-col chunk (rows are per-wave)
  #pragma unroll
  for (int r = 0; r < 4; ++r) {
    float m = fmaxf(-acc[r][0], -acc[r][1]);
    m = waveMax(m);
    float l = __expf(-acc[r][0] - m) + __expf(-acc[r][1] - m);
    l = waveSum(l);
    if (ln == 0) {
      pRM[bx * NN + i0 + w * 4 + r] = m;
      pRL[bx * NN + i0 + w * 4 + r] = l;
    }
  }

  // col-stat partials over this 16-row tile
  #pragma unroll
  for (int c = 0; c < 2; ++c) {
    float m = fmaxf(fmaxf(-acc[0][c], -acc[1][c]), fmaxf(-acc[2][c], -acc[3][c]));
    float l = __expf(-acc[0][c] - m) + __expf(-acc[1][c] - m) +
              __expf(-acc[2][c] - m) + __expf(-acc[3][c] - m);
    cmS[w][ln * 2 + c] = m;
    clS[w][ln * 2 + c] = l;
  }
  __syncthreads();
  if (t < 128) {
    const int j = t;
    const float m0 = cmS[0][j], m1 = cmS[1][j], m2 = cmS[2][j], m3 = cmS[3][j];
    const float M = fmaxf(fmaxf(m0, m1), fmaxf(m2, m3));
    const float L = clS[0][j] * __expf(m0 - M) + clS[1][j] * __expf(m1 - M) +
                    clS[2][j] * __expf(m2 - M) + clS[3][j] * __expf(m3 - M);
    pCM[by * NN + bx * 128 + j] = M;
    pCL[by * NN + bx * 128 + j] = L;
  }
}

// 20 blocks x 256. Blocks 0..15: columns (64 cols each; 4 fold-groups of 16
// partials, LDS-merged). Blocks 16..19: rows (256 rows each, fold 8).
__global__ __launch_bounds__(256)
void combine_kernel(const float* __restrict__ pRM, const float* __restrict__ pRL,
                    const float* __restrict__ pCM, const float* __restrict__ pCL,
                    float* __restrict__ rmax, float* __restrict__ rsum,
                    float* __restrict__ cmax, float* __restrict__ csum,
                    float* __restrict__ accum) {
  const int b = blockIdx.x, t = threadIdx.x;
  if (b == 0 && t == 0) {
    accum[0] = 0.f; accum[1] = 0.f; ((unsigned int*)accum)[2] = 0u;
  }
  if (b < 16) {
    __shared__ float sm[4][64], sl[4][64];
    const int c = t & 63;            // local col
    const int g = t >> 6;            // fold group 0..3 (16 partials each)
    const int j = b * 64 + c;
    float m = -1e30f;
    #pragma unroll
    for (int k = 0; k < 16; ++k) m = fmaxf(m, pCM[(g * 16 + k) * NN + j]);
    float l = 0.f;
    #pragma unroll
    for (int k = 0; k < 16; ++k)
      l += __expf(pCM[(g * 16 + k) * NN + j] - m) * pCL[(g * 16 + k) * NN + j];
    sm[g][c] = m; sl[g][c] = l;
    __syncthreads();
    if (g == 0) {
      const float m0 = sm[0][c], m1 = sm[1][c], m2 = sm[2][c], m3 = sm[3][c];
      const float M = fmaxf(fmaxf(m0, m1), fmaxf(m2, m3));
      const float L = sl[0][c] * __expf(m0 - M) + sl[1][c] * __expf(m1 - M) +
                      sl[2][c] * __expf(m2 - M) + sl[3][c] * __expf(m3 - M);
      cmax[j] = M; csum[j] = L;
    }
  } else {
    const int r = (b - 16) * 256 + t;
    float mk[8], lk[8];
    #pragma unroll
    for (int k = 0; k < 8; ++k) { mk[k] = pRM[k * NN + r]; lk[k] = pRL[k * NN + r]; }
    float m = mk[0];
    #pragma unroll
    for (int k = 1; k < 8; ++k) m = fmaxf(m, mk[k]);
    float l = 0.f;
    #pragma unroll
    for (int k = 0; k < 8; ++k) l += lk[k] * __expf(mk[k] - m);
    rmax[r] = m; rsum[r] = l;
  }
}

// 512 blocks x 2 rows: u = a+b-a*b, reduce, atomic; LAST block divides.
__global__ __launch_bounds__(256)
void final_kernel(const float* __restrict__ S,
                  const float* __restrict__ rmax, const float* __restrict__ rsum,
                  const float* __restrict__ cmax, const float* __restrict__ csum,
                  float* __restrict__ accum, float* __restrict__ out) {
  __shared__ float redn[4], redd[4];
  const int t = threadIdx.x;
  const int row0 = blockIdx.x * 2;
  const float4* S4 = (const float4*)S;
  const float4 cm = ((const float4*)cmax)[t];
  const float4 cs = ((const float4*)csum)[t];
  float un = 0.f, ud = 0.f;
  #pragma unroll
  for (int r = 0; r < 2; ++r) {
    const int row = row0 + r;
    const float rm = rmax[row];
    const float ri = 1.f / rsum[row];
    const float4 p = S4[row * NQ + t];
    {
      const float s = -p.x;
      const float a = __expf(s - rm) * ri;
      const float b = __expf(s - cm.x) / cs.x;
      const float u = a + b - a * b;
      un += u * s; ud += u;
    }
    {
      const float s = -p.y;
      const float a = __expf(s - rm) * ri;
      const float b = __expf(s - cm.y) / cs.y;
      const float u = a + b - a * b;
      un += u * s; ud += u;
    }
    {
      const float s = -p.z;
      const float a = __expf(s - rm) * ri;
      const float b = __expf(s - cm.z) / cs.z;
      const float u = a + b - a * b;
      un += u * s; ud += u;
    }
    {
      const float s = -p.w;
      const float a = __expf(s - rm) * ri;
      const float b = __expf(s - cm.w) / cs.w;
      const float u = a + b - a * b;
      un += u * s; ud += u;
    }
  }
  un = waveSum(un); ud = waveSum(ud);
  if ((t & 63) == 0) { redn[t >> 6] = un; redd[t >> 6] = ud; }
  __syncthreads();
  if (t == 0) {
    atomicAdd(&accum[0], redn[0] + redn[1] + redn[2] + redn[3]);
    atomicAdd(&accum[1], redd[0] + redd[1] + redd[2] + redd[3]);
    __threadfence();
    unsigned int* cnt = (unsigned int*)accum + 2;
    const unsigned int old = atomicAdd(cnt, 1u);
    if (old == gridDim.x - 1) {
      const float n = atomicAdd(&accum[0], 0.f);
      const float d = atomicAdd(&accum[1], 0.f);
      out[0] = n / d;
    }
  }
}

// ---------------- fallback path (R2, ws >= ~148 KB, proven) ----------------

#define TJ  128
#define NCH (NN / TJ)
#define BLK 256

__global__ __launch_bounds__(BLK)
void stats2_kernel(const float* __restrict__ zx, const float* __restrict__ zy,
                   float* __restrict__ partM, float* __restrict__ partS) {
  const int side = blockIdx.z;
  const float* __restrict__ X = side ? zy : zx;
  const float* __restrict__ Y = side ? zx : zy;
  const int j0 = blockIdx.x * TJ;
  const int i0 = blockIdx.y * 8;
  const int t  = threadIdx.x;
  const int rg = t >> 5;
  const int c  = t & 31;

  __shared__ float xs[8 * DD];
  for (int k = t; k < 8 * DD; k += BLK)
    xs[k] = X[(k >> 3) * NN + i0 + (k & 7)];
  __syncthreads();

  const float4* __restrict__ Y4 = (const float4*)Y;
  const int yb = (j0 >> 2) + c;
  float4 acc = make_float4(0.f, 0.f, 0.f, 0.f);
  #pragma unroll 8
  for (int d = 0; d < DD; ++d) {
    const float4 yv = Y4[d * NQ + yb];
    const float xv = xs[d * 8 + rg];
    acc.x += fabsf(xv - yv.x);
    acc.y += fabsf(xv - yv.y);
    acc.z += fabsf(xv - yv.z);
    acc.w += fabsf(xv - yv.w);
  }

  float m = fmaxf(fmaxf(-acc.x, -acc.y), fmaxf(-acc.z, -acc.w));
  #pragma unroll
  for (int off = 16; off > 0; off >>= 1) m = fmaxf(m, __shfl_xor(m, off, 32));
  float p = __expf(-acc.x - m) + __expf(-acc.y - m) +
            __expf(-acc.z - m) + __expf(-acc.w - m);
  #pragma unroll
  for (int off = 16; off > 0; off >>= 1) p += __shfl_xor(p, off, 32);

  if (c == 0) {
    const int idx = side * (NCH * NN) + blockIdx.x * NN + (i0 + rg);
    partM[idx] = m;
    partS[idx] = p;
  }
}

__global__ __launch_bounds__(BLK)
void combine_kernel_fb(const float* __restrict__ partM, const float* __restrict__ partS,
                       float* __restrict__ rmax, float* __restrict__ rsum,
                       float* __restrict__ cmax, float* __restrict__ csum,
                       float* __restrict__ accum) {
  const int gid = blockIdx.x * BLK + threadIdx.x;
  if (gid == 0) { accum[0] = 0.f; accum[1] = 0.f; }
  const int sd = gid >> 10;
  const int i  = gid & (NN - 1);
  float mk[NCH], sk[NCH];
  #pragma unroll
  for (int k = 0; k < NCH; ++k) {
    mk[k] = partM[sd * (NCH * NN) + k * NN + i];
    sk[k] = partS[sd * (NCH * NN) + k * NN + i];
  }
  float m = mk[0];
  #pragma unroll
  for (int k = 1; k < NCH; ++k) m = fmaxf(m, mk[k]);
  float s = 0.f;
  #pragma unroll
  for (int k = 0; k < NCH; ++k) s += __expf(mk[k] - m) * sk[k];
  if (sd == 0) { rmax[i] = m; rsum[i] = s; }
  else         { cmax[i] = m; csum[i] = s; }
}

__global__ __launch_bounds__(BLK)
void final2_kernel(const float* __restrict__ zx, const float* __restrict__ zy,
                   const float* __restrict__ rmax, const float* __restrict__ rsum,
                   const float* __restrict__ cmax, const float* __restrict__ csum,
                   float* __restrict__ accum) {
  const int j0 = blockIdx.x * TJ;
  const int i0 = blockIdx.y * 8;
  const int t  = threadIdx.x;
  const int rg = t >> 5;
  const int c  = t & 31;

  __shared__ float xs[8 * DD];
  __shared__ float redn[4], redd[4];
  for (int k = t; k < 8 * DD; k += BLK)
    xs[k] = zx[(k >> 3) * NN + i0 + (k & 7)];
  __syncthreads();

  const float4* __restrict__ Y4 = (const float4*)zy;
  const int yb = (j0 >> 2) + c;
  float4 acc = make_float4(0.f, 0.f, 0.f, 0.f);
  #pragma unroll 8
  for (int d = 0; d < DD; ++d) {
    const float4 yv = Y4[d * NQ + yb];
    const float xv = xs[d * 8 + rg];
    acc.x += fabsf(xv - yv.x);
    acc.y += fabsf(xv - yv.y);
    acc.z += fabsf(xv - yv.z);
    acc.w += fabsf(xv - yv.w);
  }

  const int i = i0 + rg;
  const float rm = rmax[i];
  const float ri = 1.f / rsum[i];
  const float4 cm = ((const float4*)cmax)[yb];
  const float4 cs = ((const float4*)csum)[yb];

  float un = 0.f, ud = 0.f;
  {
    const float s = -acc.x;
    const float a = __expf(s - rm) * ri;
    const float b = __expf(s - cm.x) / cs.x;
    const float u = a + b - a * b;
    un += u * s; ud += u;
  }
  {
    const float s = -acc.y;
    const float a = __expf(s - rm) * ri;
    const float b = __expf(s - cm.y) / cs.y;
    const float u = a + b - a * b;
    un += u * s; ud += u;
  }
  {
    const float s = -acc.z;
    const float a = __expf(s - rm) * ri;
    const float b = __expf(s - cm.z) / cs.z;
    const float u = a + b - a * b;
    un += u * s; ud += u;
  }
  {
    const float s = -acc.w;
    const float a = __expf(s - rm) * ri;
    const float b = __expf(s - cm.w) / cs.w;
    const float u = a + b - a * b;
    un += u * s; ud += u;
  }

  un = waveSum(un); ud = waveSum(ud);
  if ((t & 63) == 0) { redn[t >> 6] = un; redd[t >> 6] = ud; }
  __syncthreads();
  if (t == 0) {
    atomicAdd(&accum[0], redn[0] + redn[1] + redn[2] + redn[3]);
    atomicAdd(&accum[1], redd[0] + redd[1] + redd[2] + redd[3]);
  }
}

__global__ void finalize_kernel(const float* __restrict__ accum, float* __restrict__ out) {
  out[0] = accum[0] / accum[1];
}

// ---------------------------------------------------------------------------

extern "C" void kernel_launch(void* const* d_in, const int* in_sizes, int n_in,
                              void* d_out, int out_size, void* d_ws, size_t ws_size,
                              hipStream_t stream) {
  const float* zx = (const float*)d_in[0];   // (1, D, N): X[d*N + i]
  const float* zy = (const float*)d_in[1];   // (1, D, M): Y[d*M + j]
  float* ws  = (float*)d_ws;
  float* out = (float*)d_out;

  // fast-path ws layout (floats): ~4.8 MB
  float* accum = ws;                         // [0]=num, [1]=den, [2]=ticket
  float* S     = ws + 16;                    // 1M floats (4 MB)
  float* pRM   = S + NN * NN;                // 8 * 1024
  float* pRL   = pRM + 8 * NN;
  float* pCM   = pRL + 8 * NN;               // 64 * 1024
  float* pCL   = pCM + 64 * NN;
  float* rmax  = pCL + 64 * NN;
  float* rsum  = rmax + NN;
  float* cmax  = rsum + NN;
  float* csum  = cmax + NN;
  const size_t need = (size_t)((csum + NN) - ws) * sizeof(float);

  if (ws_size >= need) {
    dim3 g1(8, 64);                          // 512 blocks
    scompute_kernel<<<g1, 256, 0, stream>>>(zx, zy, S, pRM, pRL, pCM, pCL);
    combine_kernel<<<20, 256, 0, stream>>>(pRM, pRL, pCM, pCL,
                                           rmax, rsum, cmax, csum, accum);
    final_kernel<<<NN / 2, 256, 0, stream>>>(S, rmax, rsum, cmax, csum, accum, out);
  } else {
    // R2 fallback (~148 KB)
    float* partM = ws + 16;
    float* partS = partM + 2 * NCH * NN;
    float* frmax = partS + 2 * NCH * NN;
    float* frsum = frmax + NN;
    float* fcmax = frsum + NN;
    float* fcsum = fcmax + NN;
    dim3 sgrid(NCH, NN / 8, 2);
    stats2_kernel<<<sgrid, BLK, 0, stream>>>(zx, zy, partM, partS);
    combine_kernel_fb<<<(2 * NN) / BLK, BLK, 0, stream>>>(partM, partS,
                                                          frmax, frsum, fcmax, fcsum, accum);
    dim3 fgrid(NCH, NN / 8);
    final2_kernel<<<fgrid, BLK, 0, stream>>>(zx, zy, frmax, frsum, fcmax, fcsum, accum);
    finalize_kernel<<<1, 1, 0, stream>>>(accum, out);
  }
}